// Round 9
// baseline (108.858 us; speedup 1.0000x reference)
//
#include <hip/hip_runtime.h>
#include <hip/hip_fp16.h>

// FLAME mesh SE3 extraction: T=128 frames, V=5023 vertices, K=16 neighbors.
// R9: 2-vertex ILP interleave. R8 fixed numerics (fp16 LDS records + f32
// accumulation, absmax 3.9e-3); kernel ~29us vs ~6.5us VALU / ~5us LDS floors
// -> latency-bound at 4 waves/SIMD (R6: more waves impossible, VGPR<=64
// spills). So double per-wave ILP: each thread runs TWO independent vertex
// pipelines (state as [N] arrays, fully unrolled -> scheduler interleaves the
// gather/cov/Newton chains). Pair (v, v+512) always in range; tail tid<~232.
// Config unchanged: 512 blk x 512 thr, 80,368 B LDS, 2 blocks/CU, VGPR<=128.

namespace {
constexpr int T_FRAMES = 128;
constexpr int V_NUM    = 5023;
constexpr int K_NB     = 16;
constexpr int SLAB     = V_NUM * 3;            // floats per frame per array
constexpr int VPB      = 1256;                 // vertices per block quarter
constexpr int LDS_BYTES = V_NUM * 16;          // 80,368 B -> 2 blocks/CU
}

union VRec {
    uint4   u;
    __half2 h[4];   // h[0]=(cx,cy) h[1]=(cz,dx) h[2]=(dy,dz) h[3]=pad
};

template<int N>
__device__ __forceinline__ void process_vertices(
    const int* vv, const uint4* __restrict__ ldsv,
    const int* __restrict__ nbr, const unsigned char* __restrict__ mask_raw,
    int mflag, int t, float* __restrict__ out)
{
    // ---- mask -> 16-bit words ----
    unsigned mbits[N];
    #pragma unroll
    for (int u = 0; u < N; ++u) {
        const int v = vv[u];
        unsigned mb = 0;
        if (mflag == 1) {
            const uint4 mw = *reinterpret_cast<const uint4*>(mask_raw + (size_t)v * K_NB);
            const unsigned w[4] = {mw.x, mw.y, mw.z, mw.w};
            #pragma unroll
            for (int j = 0; j < 4; ++j) {
                mb |= (((w[j]       ) & 0xffu) != 0u ? 1u : 0u) << (j*4+0);
                mb |= (((w[j] >> 8  ) & 0xffu) != 0u ? 1u : 0u) << (j*4+1);
                mb |= (((w[j] >> 16 ) & 0xffu) != 0u ? 1u : 0u) << (j*4+2);
                mb |= (((w[j] >> 24 ) & 0xffu) != 0u ? 1u : 0u) << (j*4+3);
            }
        } else if (mflag == 0) {
            const int* mp = reinterpret_cast<const int*>(mask_raw) + (size_t)v * K_NB;
            #pragma unroll
            for (int k = 0; k < K_NB; ++k) mb |= (mp[k] ? 1u : 0u) << k;
        } else {
            const float* mp = reinterpret_cast<const float*>(mask_raw) + (size_t)v * K_NB;
            #pragma unroll
            for (int k = 0; k < K_NB; ++k) mb |= ((mp[k] != 0.0f) ? 1u : 0u) << k;
        }
        mbits[u] = mb;
    }

    // ---- self vertices (fp16 LDS -> f32) ----
    float cvx[N], cvy[N], cvz[N], dvx[N], dvy[N], dvz[N];
    #pragma unroll
    for (int u = 0; u < N; ++u) {
        VRec r; r.u = ldsv[vv[u]];
        const float2 f0 = __half22float2(r.h[0]);
        const float2 f1 = __half22float2(r.h[1]);
        const float2 f2 = __half22float2(r.h[2]);
        cvx[u] = f0.x; cvy[u] = f0.y; cvz[u] = f1.x;
        dvx[u] = f1.y; dvy[u] = f2.x; dvz[u] = f2.y;
    }

    // ---- covariance, N interleaved pipelines; f32 math, fp16 inputs ----
    float a00[N], a01[N], a02[N], a10[N], a11[N], a12[N], a20[N], a21[N], a22[N];
    #pragma unroll
    for (int u = 0; u < N; ++u) {
        a00[u]=0.f; a01[u]=0.f; a02[u]=0.f;
        a10[u]=0.f; a11[u]=0.f; a12[u]=0.f;
        a20[u]=0.f; a21[u]=0.f; a22[u]=0.f;
    }
    #pragma unroll
    for (int g = 0; g < 4; ++g) {
        int4 nq[N];
        #pragma unroll
        for (int u = 0; u < N; ++u)
            nq[u] = reinterpret_cast<const int4*>(nbr + (size_t)vv[u] * K_NB)[g];
        #pragma unroll
        for (int j = 0; j < 4; ++j) {
            #pragma unroll
            for (int u = 0; u < N; ++u) {
                const int ni = (j == 0) ? nq[u].x : (j == 1) ? nq[u].y
                             : (j == 2) ? nq[u].z : nq[u].w;
                VRec r; r.u = ldsv[ni];
                const float m = ((mbits[u] >> (g*4+j)) & 1u) ? 1.0f : 0.0f;
                const float2 f0 = __half22float2(r.h[0]);   // cx, cy
                const float2 f1 = __half22float2(r.h[1]);   // cz, dx
                const float2 f2 = __half22float2(r.h[2]);   // dy, dz
                const float px = fmaf(f0.x, m, -cvx[u]);
                const float py = fmaf(f0.y, m, -cvy[u]);
                const float pz = fmaf(f1.x, m, -cvz[u]);
                const float qx = fmaf(f1.y, m, -dvx[u]);
                const float qy = fmaf(f2.x, m, -dvy[u]);
                const float qz = fmaf(f2.y, m, -dvz[u]);
                a00[u] = fmaf(px,qx,a00[u]); a01[u] = fmaf(px,qy,a01[u]); a02[u] = fmaf(px,qz,a02[u]);
                a10[u] = fmaf(py,qx,a10[u]); a11[u] = fmaf(py,qy,a11[u]); a12[u] = fmaf(py,qz,a12[u]);
                a20[u] = fmaf(pz,qx,a20[u]); a21[u] = fmaf(pz,qy,a21[u]); a22[u] = fmaf(pz,qz,a22[u]);
            }
        }
    }

    // ---- polar(A^T) Newton, N interleaved chains ----
    float x00[N],x01[N],x02[N],x10[N],x11[N],x12[N],x20[N],x21[N],x22[N];
    #pragma unroll
    for (int u = 0; u < N; ++u) {
        x00[u]=a00[u]; x01[u]=a10[u]; x02[u]=a20[u];
        x10[u]=a01[u]; x11[u]=a11[u]; x12[u]=a21[u];
        x20[u]=a02[u]; x21[u]=a12[u]; x22[u]=a22[u];
        const float d0 = x00[u]*(x11[u]*x22[u] - x12[u]*x21[u])
                       - x01[u]*(x10[u]*x22[u] - x12[u]*x20[u])
                       + x02[u]*(x10[u]*x21[u] - x11[u]*x20[u]);
        const float ad = fmaxf(fabsf(d0), 1e-30f);
        float mu = __builtin_amdgcn_exp2f(-0.3333333333f *
                                          __builtin_amdgcn_logf(ad));
        if (d0 < 0.0f) mu = -mu;
        x00[u]*=mu; x01[u]*=mu; x02[u]*=mu;
        x10[u]*=mu; x11[u]*=mu; x12[u]*=mu;
        x20[u]*=mu; x21[u]*=mu; x22[u]*=mu;
    }
    #pragma unroll
    for (int it = 0; it < 6; ++it) {
        #pragma unroll
        for (int u = 0; u < N; ++u) {
            const float c00 = x11[u]*x22[u] - x12[u]*x21[u];
            const float c01 = x12[u]*x20[u] - x10[u]*x22[u];
            const float c02 = x10[u]*x21[u] - x11[u]*x20[u];
            const float c10 = x02[u]*x21[u] - x01[u]*x22[u];
            const float c11 = x00[u]*x22[u] - x02[u]*x20[u];
            const float c12 = x01[u]*x20[u] - x00[u]*x21[u];
            const float c20 = x01[u]*x12[u] - x02[u]*x11[u];
            const float c21 = x02[u]*x10[u] - x00[u]*x12[u];
            const float c22 = x00[u]*x11[u] - x01[u]*x10[u];
            const float det = x00[u]*c00 + x01[u]*c01 + x02[u]*c02;   // ~ +1
            const float r   = 0.5f * __builtin_amdgcn_rcpf(det);
            x00[u] = fmaf(0.5f, x00[u], r*c00); x01[u] = fmaf(0.5f, x01[u], r*c01); x02[u] = fmaf(0.5f, x02[u], r*c02);
            x10[u] = fmaf(0.5f, x10[u], r*c10); x11[u] = fmaf(0.5f, x11[u], r*c11); x12[u] = fmaf(0.5f, x12[u], r*c12);
            x20[u] = fmaf(0.5f, x20[u], r*c20); x21[u] = fmaf(0.5f, x21[u], r*c21); x22[u] = fmaf(0.5f, x22[u], r*c22);
        }
    }

    // ---- quaternion (argmax over squares == reference argmax) + stores ----
    #pragma unroll
    for (int u = 0; u < N; ++u) {
        const float s0 = fmaxf(1.0f + x00[u] + x11[u] + x22[u], 0.0f);
        const float s1 = fmaxf(1.0f + x00[u] - x11[u] - x22[u], 0.0f);
        const float s2 = fmaxf(1.0f - x00[u] + x11[u] - x22[u], 0.0f);
        const float s3 = fmaxf(1.0f - x00[u] - x11[u] + x22[u], 0.0f);

        int best = 0; float bs = s0;        // first-max tie-break = jnp.argmax
        if (s1 > bs) { best = 1; bs = s1; }
        if (s2 > bs) { best = 2; bs = s2; }
        if (s3 > bs) { best = 3; bs = s3; }
        const float bq = sqrtf(bs);

        float r0, r1, r2, r3;
        if      (best == 0) { r0 = bs;              r1 = x21[u]-x12[u]; r2 = x02[u]-x20[u]; r3 = x10[u]-x01[u]; }
        else if (best == 1) { r0 = x21[u]-x12[u];   r1 = bs;            r2 = x01[u]+x10[u]; r3 = x02[u]+x20[u]; }
        else if (best == 2) { r0 = x02[u]-x20[u];   r1 = x10[u]+x01[u]; r2 = bs;            r3 = x12[u]+x21[u]; }
        else                { r0 = x10[u]-x01[u];   r1 = x20[u]+x02[u]; r2 = x21[u]+x12[u]; r3 = bs;            }
        const float qi = __builtin_amdgcn_rcpf(2.0f * fmaxf(bq, 0.1f));

        const size_t base_q = ((size_t)t * V_NUM + vv[u]) * 4;
        float4 qout;
        qout.x = r0 * qi; qout.y = r1 * qi; qout.z = r2 * qi; qout.w = r3 * qi;
        *reinterpret_cast<float4*>(out + base_q) = qout;

        const size_t base_t = (size_t)T_FRAMES * V_NUM * 4 + ((size_t)t * V_NUM + vv[u]) * 3;
        out[base_t+0] = dvx[u] - cvx[u];
        out[base_t+1] = dvy[u] - cvy[u];
        out[base_t+2] = dvz[u] - cvz[u];
    }
}

__global__ __launch_bounds__(512, 4)
void se3_extract_kernel(const float* __restrict__ cano,
                        const float* __restrict__ defo,
                        const int*   __restrict__ nbr,
                        const unsigned char* __restrict__ mask_raw,
                        float* __restrict__ out) {
    extern __shared__ uint4 ldsv[];   // [V_NUM] packed fp16 cano+defo

    const int bid  = blockIdx.x;
    const int t    = bid & 127;       // frame
    const int quar = bid >> 7;        // 0..3 -> vertex quarter
    const int tid  = threadIdx.x;

    // ---- per-wave mask dtype detect from first 256 B (L2-broadcast).
    //      flag: 0=int32, 1=bool, 2=f32. ----
    int mflag;
    {
        const unsigned w = reinterpret_cast<const unsigned*>(mask_raw)[tid & 63];
        const bool isb = ((((w >> 8) & 0xffu) == 1u) | (((w >> 24) & 0xffu) == 1u));
        const bool isf = ((w >> 24) == 0x3fu);
        const unsigned long long mb = __ballot(isb);
        const unsigned long long mf = __ballot(isf);
        mflag = 0;
        if (__popcll(mb) > 16)      mflag = 1;
        else if (__popcll(mf) > 16) mflag = 2;
    }

    // ---- stage full frame into LDS as packed fp16 records ----
    {
        const float* __restrict__ cfp = cano + (size_t)t * SLAB;
        const float* __restrict__ dfp = defo + (size_t)t * SLAB;
        for (int i = tid; i < V_NUM; i += 512) {
            const float* cp = cfp + i * 3;
            const float* dp = dfp + i * 3;
            VRec r;
            r.h[0] = __floats2half2_rn(cp[0], cp[1]);
            r.h[1] = __floats2half2_rn(cp[2], dp[0]);
            r.h[2] = __floats2half2_rn(dp[1], dp[2]);
            r.h[3] = __floats2half2_rn(0.0f, 0.0f);
            ldsv[i] = r.u;
        }
    }
    __syncthreads();

    const int vbeg = quar * VPB;
    const int vend = (quar == 3) ? V_NUM : vbeg + VPB;

    // main pair: (v, v+512) -- always in range (quarter size >= 1255 > 1023)
    {
        const int vv[2] = { vbeg + tid, vbeg + tid + 512 };
        process_vertices<2>(vv, ldsv, nbr, mask_raw, mflag, t, out);
    }
    // tail single: v + 1024 (tid < ~232)
    {
        const int v2 = vbeg + tid + 1024;
        if (v2 < vend) {
            const int vv[1] = { v2 };
            process_vertices<1>(vv, ldsv, nbr, mask_raw, mflag, t, out);
        }
    }
}

extern "C" void kernel_launch(void* const* d_in, const int* in_sizes, int n_in,
                              void* d_out, int out_size, void* d_ws, size_t ws_size,
                              hipStream_t stream) {
    const float* cano = (const float*)d_in[0];
    const float* defo = (const float*)d_in[1];
    const int*   nbr  = (const int*)d_in[2];
    const unsigned char* mask = (const unsigned char*)d_in[3];
    float* out = (float*)d_out;

    // Allow ~78.5 KB dynamic LDS (host-side config, idempotent).
    static bool attr_set = false;
    if (!attr_set) {
        (void)hipFuncSetAttribute((const void*)se3_extract_kernel,
                                  hipFuncAttributeMaxDynamicSharedMemorySize,
                                  LDS_BYTES);
        attr_set = true;
    }

    // 4 blocks per frame (vertex quarters); t = bid & 127; 2 blocks/CU,
    // 16 waves/CU, VGPR <= 128 (no spill).
    se3_extract_kernel<<<512, 512, LDS_BYTES, stream>>>(cano, defo, nbr, mask, out);
}

// Round 10
// 102.924 us; speedup vs baseline: 1.0577x; 1.0577x over previous
//
#include <hip/hip_runtime.h>
#include <hip/hip_fp16.h>

// FLAME mesh SE3 extraction: T=128 frames, V=5023 vertices, K=16 neighbors.
// R10: partial ILP-2. R9's full 2-vertex interleave spilled (WRITE 89 MB,
// 46us kernel): 2x(9 acc + 9 Newton + temps) > 128-VGPR budget. Fix: only the
// COVARIANCE loops (the LDS-latency-bound part) are interleaved for the pair
// (v, v+512); Newton/quat/store run sequentially per vertex (ALU-only, hidden
// by other waves). sched_barrier(0) between epilogues keeps the scheduler
// from re-merging them. Numerics identical to R8 (fp16 LDS records, f32
// accumulation -- fp16 acc failed in R7; 6 Newton iters; argmax over squares).
// Config: 512 blk x 512 thr, 80,368 B LDS, 2 blocks/CU, VGPR<=128.
// Known: dur_us = kernel + ~63us fixed harness overhead (R6/R9 decomposition).

namespace {
constexpr int T_FRAMES = 128;
constexpr int V_NUM    = 5023;
constexpr int K_NB     = 16;
constexpr int SLAB     = V_NUM * 3;            // floats per frame per array
constexpr int VPB      = 1256;                 // vertices per block quarter
constexpr int LDS_BYTES = V_NUM * 16;          // 80,368 B -> 2 blocks/CU
}

union VRec {
    uint4   u;
    __half2 h[4];   // h[0]=(cx,cy) h[1]=(cz,dx) h[2]=(dy,dz) h[3]=pad
};

__device__ __forceinline__ unsigned decode_mask(
    const unsigned char* __restrict__ mask_raw, int v, int mflag)
{
    unsigned mb = 0;
    if (mflag == 1) {
        const uint4 mw = *reinterpret_cast<const uint4*>(mask_raw + (size_t)v * K_NB);
        const unsigned w[4] = {mw.x, mw.y, mw.z, mw.w};
        #pragma unroll
        for (int j = 0; j < 4; ++j) {
            mb |= (((w[j]       ) & 0xffu) != 0u ? 1u : 0u) << (j*4+0);
            mb |= (((w[j] >> 8  ) & 0xffu) != 0u ? 1u : 0u) << (j*4+1);
            mb |= (((w[j] >> 16 ) & 0xffu) != 0u ? 1u : 0u) << (j*4+2);
            mb |= (((w[j] >> 24 ) & 0xffu) != 0u ? 1u : 0u) << (j*4+3);
        }
    } else if (mflag == 0) {
        const int* mp = reinterpret_cast<const int*>(mask_raw) + (size_t)v * K_NB;
        #pragma unroll
        for (int k = 0; k < K_NB; ++k) mb |= (mp[k] ? 1u : 0u) << k;
    } else {
        const float* mp = reinterpret_cast<const float*>(mask_raw) + (size_t)v * K_NB;
        #pragma unroll
        for (int k = 0; k < K_NB; ++k) mb |= ((mp[k] != 0.0f) ? 1u : 0u) << k;
    }
    return mb;
}

// Newton polar + quaternion + stores for ONE vertex (ALU-only epilogue).
__device__ __forceinline__ void finish_vertex(
    float a00, float a01, float a02,
    float a10, float a11, float a12,
    float a20, float a21, float a22,
    float cvx, float cvy, float cvz,
    float dvx, float dvy, float dvz,
    int t, int v, float* __restrict__ out)
{
    // R = polar(A^T): scale once by sign*|det|^(-1/3), then Newton
    // X <- 0.5*X + 0.5*cof(X)/det(X), 6 iters.
    float x00=a00, x01=a10, x02=a20;
    float x10=a01, x11=a11, x12=a21;
    float x20=a02, x21=a12, x22=a22;
    {
        const float d0 = x00*(x11*x22 - x12*x21)
                       - x01*(x10*x22 - x12*x20)
                       + x02*(x10*x21 - x11*x20);
        const float ad = fmaxf(fabsf(d0), 1e-30f);
        float mu = __builtin_amdgcn_exp2f(-0.3333333333f *
                                          __builtin_amdgcn_logf(ad));
        if (d0 < 0.0f) mu = -mu;
        x00*=mu; x01*=mu; x02*=mu;
        x10*=mu; x11*=mu; x12*=mu;
        x20*=mu; x21*=mu; x22*=mu;
    }
    #pragma unroll
    for (int it = 0; it < 6; ++it) {
        const float c00 = x11*x22 - x12*x21;
        const float c01 = x12*x20 - x10*x22;
        const float c02 = x10*x21 - x11*x20;
        const float c10 = x02*x21 - x01*x22;
        const float c11 = x00*x22 - x02*x20;
        const float c12 = x01*x20 - x00*x21;
        const float c20 = x01*x12 - x02*x11;
        const float c21 = x02*x10 - x00*x12;
        const float c22 = x00*x11 - x01*x10;
        const float det = x00*c00 + x01*c01 + x02*c02;   // ~ +1
        const float r   = 0.5f * __builtin_amdgcn_rcpf(det);
        x00 = fmaf(0.5f, x00, r*c00); x01 = fmaf(0.5f, x01, r*c01); x02 = fmaf(0.5f, x02, r*c02);
        x10 = fmaf(0.5f, x10, r*c10); x11 = fmaf(0.5f, x11, r*c11); x12 = fmaf(0.5f, x12, r*c12);
        x20 = fmaf(0.5f, x20, r*c20); x21 = fmaf(0.5f, x21, r*c21); x22 = fmaf(0.5f, x22, r*c22);
    }

    // quaternion: argmax over candidate squares (monotone == reference argmax)
    const float s0 = fmaxf(1.0f + x00 + x11 + x22, 0.0f);
    const float s1 = fmaxf(1.0f + x00 - x11 - x22, 0.0f);
    const float s2 = fmaxf(1.0f - x00 + x11 - x22, 0.0f);
    const float s3 = fmaxf(1.0f - x00 - x11 + x22, 0.0f);

    int best = 0; float bs = s0;            // first-max tie-break = jnp.argmax
    if (s1 > bs) { best = 1; bs = s1; }
    if (s2 > bs) { best = 2; bs = s2; }
    if (s3 > bs) { best = 3; bs = s3; }
    const float bq = sqrtf(bs);

    float r0, r1, r2, r3;
    if      (best == 0) { r0 = bs;      r1 = x21-x12; r2 = x02-x20; r3 = x10-x01; }
    else if (best == 1) { r0 = x21-x12; r1 = bs;      r2 = x01+x10; r3 = x02+x20; }
    else if (best == 2) { r0 = x02-x20; r1 = x10+x01; r2 = bs;      r3 = x12+x21; }
    else                { r0 = x10-x01; r1 = x20+x02; r2 = x21+x12; r3 = bs;      }
    const float qi = __builtin_amdgcn_rcpf(2.0f * fmaxf(bq, 0.1f));

    const size_t base_q = ((size_t)t * V_NUM + v) * 4;
    float4 qout;
    qout.x = r0 * qi; qout.y = r1 * qi; qout.z = r2 * qi; qout.w = r3 * qi;
    *reinterpret_cast<float4*>(out + base_q) = qout;

    const size_t base_t = (size_t)T_FRAMES * V_NUM * 4 + ((size_t)t * V_NUM + v) * 3;
    out[base_t+0] = dvx - cvx;
    out[base_t+1] = dvy - cvy;
    out[base_t+2] = dvz - cvz;
}

__global__ __launch_bounds__(512, 4)
void se3_extract_kernel(const float* __restrict__ cano,
                        const float* __restrict__ defo,
                        const int*   __restrict__ nbr,
                        const unsigned char* __restrict__ mask_raw,
                        float* __restrict__ out) {
    extern __shared__ uint4 ldsv[];   // [V_NUM] packed fp16 cano+defo

    const int bid  = blockIdx.x;
    const int t    = bid & 127;       // frame
    const int quar = bid >> 7;        // 0..3 -> vertex quarter
    const int tid  = threadIdx.x;

    // ---- per-wave mask dtype detect from first 256 B (L2-broadcast).
    //      flag: 0=int32, 1=bool, 2=f32. ----
    int mflag;
    {
        const unsigned w = reinterpret_cast<const unsigned*>(mask_raw)[tid & 63];
        const bool isb = ((((w >> 8) & 0xffu) == 1u) | (((w >> 24) & 0xffu) == 1u));
        const bool isf = ((w >> 24) == 0x3fu);
        const unsigned long long mb = __ballot(isb);
        const unsigned long long mf = __ballot(isf);
        mflag = 0;
        if (__popcll(mb) > 16)      mflag = 1;
        else if (__popcll(mf) > 16) mflag = 2;
    }

    // ---- stage full frame into LDS as packed fp16 records ----
    {
        const float* __restrict__ cfp = cano + (size_t)t * SLAB;
        const float* __restrict__ dfp = defo + (size_t)t * SLAB;
        for (int i = tid; i < V_NUM; i += 512) {
            const float* cp = cfp + i * 3;
            const float* dp = dfp + i * 3;
            VRec r;
            r.h[0] = __floats2half2_rn(cp[0], cp[1]);
            r.h[1] = __floats2half2_rn(cp[2], dp[0]);
            r.h[2] = __floats2half2_rn(dp[1], dp[2]);
            r.h[3] = __floats2half2_rn(0.0f, 0.0f);
            ldsv[i] = r.u;
        }
    }
    __syncthreads();

    const int vbeg = quar * VPB;
    const int vend = (quar == 3) ? V_NUM : vbeg + VPB;

    // ======== main pair (v, v+512): covariance loops INTERLEAVED ========
    {
        const int v0 = vbeg + tid;
        const int v1 = v0 + 512;     // always < vend (quarter >= 1255 > 1023)
        const unsigned mb0 = decode_mask(mask_raw, v0, mflag);
        const unsigned mb1 = decode_mask(mask_raw, v1, mflag);

        float cvx0,cvy0,cvz0,dvx0,dvy0,dvz0, cvx1,cvy1,cvz1,dvx1,dvy1,dvz1;
        {
            VRec r; r.u = ldsv[v0];
            float2 f0 = __half22float2(r.h[0]);
            float2 f1 = __half22float2(r.h[1]);
            float2 f2 = __half22float2(r.h[2]);
            cvx0=f0.x; cvy0=f0.y; cvz0=f1.x; dvx0=f1.y; dvy0=f2.x; dvz0=f2.y;
            r.u = ldsv[v1];
            f0 = __half22float2(r.h[0]);
            f1 = __half22float2(r.h[1]);
            f2 = __half22float2(r.h[2]);
            cvx1=f0.x; cvy1=f0.y; cvz1=f1.x; dvx1=f1.y; dvy1=f2.x; dvz1=f2.y;
        }

        float b00=0.f,b01=0.f,b02=0.f,b10=0.f,b11=0.f,b12=0.f,b20=0.f,b21=0.f,b22=0.f;
        float e00=0.f,e01=0.f,e02=0.f,e10=0.f,e11=0.f,e12=0.f,e20=0.f,e21=0.f,e22=0.f;
        const int4* __restrict__ nb0 = reinterpret_cast<const int4*>(nbr + (size_t)v0 * K_NB);
        const int4* __restrict__ nb1 = reinterpret_cast<const int4*>(nbr + (size_t)v1 * K_NB);
        #pragma unroll
        for (int g = 0; g < 4; ++g) {
            const int4 nq0 = nb0[g];
            const int4 nq1 = nb1[g];
            #pragma unroll
            for (int j = 0; j < 4; ++j) {
                const int n0 = (j==0)?nq0.x:(j==1)?nq0.y:(j==2)?nq0.z:nq0.w;
                const int n1 = (j==0)?nq1.x:(j==1)?nq1.y:(j==2)?nq1.z:nq1.w;
                VRec r0; r0.u = ldsv[n0];           // two independent ds_reads
                VRec r1; r1.u = ldsv[n1];
                const float m0 = ((mb0 >> (g*4+j)) & 1u) ? 1.0f : 0.0f;
                const float m1 = ((mb1 >> (g*4+j)) & 1u) ? 1.0f : 0.0f;
                {
                    const float2 f0 = __half22float2(r0.h[0]);
                    const float2 f1 = __half22float2(r0.h[1]);
                    const float2 f2 = __half22float2(r0.h[2]);
                    const float px = fmaf(f0.x, m0, -cvx0);
                    const float py = fmaf(f0.y, m0, -cvy0);
                    const float pz = fmaf(f1.x, m0, -cvz0);
                    const float qx = fmaf(f1.y, m0, -dvx0);
                    const float qy = fmaf(f2.x, m0, -dvy0);
                    const float qz = fmaf(f2.y, m0, -dvz0);
                    b00 = fmaf(px,qx,b00); b01 = fmaf(px,qy,b01); b02 = fmaf(px,qz,b02);
                    b10 = fmaf(py,qx,b10); b11 = fmaf(py,qy,b11); b12 = fmaf(py,qz,b12);
                    b20 = fmaf(pz,qx,b20); b21 = fmaf(pz,qy,b21); b22 = fmaf(pz,qz,b22);
                }
                {
                    const float2 f0 = __half22float2(r1.h[0]);
                    const float2 f1 = __half22float2(r1.h[1]);
                    const float2 f2 = __half22float2(r1.h[2]);
                    const float px = fmaf(f0.x, m1, -cvx1);
                    const float py = fmaf(f0.y, m1, -cvy1);
                    const float pz = fmaf(f1.x, m1, -cvz1);
                    const float qx = fmaf(f1.y, m1, -dvx1);
                    const float qy = fmaf(f2.x, m1, -dvy1);
                    const float qz = fmaf(f2.y, m1, -dvz1);
                    e00 = fmaf(px,qx,e00); e01 = fmaf(px,qy,e01); e02 = fmaf(px,qz,e02);
                    e10 = fmaf(py,qx,e10); e11 = fmaf(py,qy,e11); e12 = fmaf(py,qz,e12);
                    e20 = fmaf(pz,qx,e20); e21 = fmaf(pz,qy,e21); e22 = fmaf(pz,qz,e22);
                }
            }
        }

        // sequential ALU epilogues; sched_barrier stops re-merging (reg blow-up)
        finish_vertex(b00,b01,b02,b10,b11,b12,b20,b21,b22,
                      cvx0,cvy0,cvz0,dvx0,dvy0,dvz0, t, v0, out);
        __builtin_amdgcn_sched_barrier(0);
        finish_vertex(e00,e01,e02,e10,e11,e12,e20,e21,e22,
                      cvx1,cvy1,cvz1,dvx1,dvy1,dvz1, t, v1, out);
    }

    // ======== tail single: v + 1024 (tid < ~232) ========
    {
        const int v2 = vbeg + tid + 1024;
        if (v2 < vend) {
            const unsigned mb2 = decode_mask(mask_raw, v2, mflag);
            float cvx2,cvy2,cvz2,dvx2,dvy2,dvz2;
            {
                VRec r; r.u = ldsv[v2];
                const float2 f0 = __half22float2(r.h[0]);
                const float2 f1 = __half22float2(r.h[1]);
                const float2 f2 = __half22float2(r.h[2]);
                cvx2=f0.x; cvy2=f0.y; cvz2=f1.x; dvx2=f1.y; dvy2=f2.x; dvz2=f2.y;
            }
            float a00=0.f,a01=0.f,a02=0.f,a10=0.f,a11=0.f,a12=0.f,a20=0.f,a21=0.f,a22=0.f;
            const int4* __restrict__ nb4 = reinterpret_cast<const int4*>(nbr + (size_t)v2 * K_NB);
            #pragma unroll
            for (int g = 0; g < 4; ++g) {
                const int4 nq = nb4[g];
                #pragma unroll
                for (int j = 0; j < 4; ++j) {
                    const int ni = (j==0)?nq.x:(j==1)?nq.y:(j==2)?nq.z:nq.w;
                    VRec r; r.u = ldsv[ni];
                    const float m = ((mb2 >> (g*4+j)) & 1u) ? 1.0f : 0.0f;
                    const float2 f0 = __half22float2(r.h[0]);
                    const float2 f1 = __half22float2(r.h[1]);
                    const float2 f2 = __half22float2(r.h[2]);
                    const float px = fmaf(f0.x, m, -cvx2);
                    const float py = fmaf(f0.y, m, -cvy2);
                    const float pz = fmaf(f1.x, m, -cvz2);
                    const float qx = fmaf(f1.y, m, -dvx2);
                    const float qy = fmaf(f2.x, m, -dvy2);
                    const float qz = fmaf(f2.y, m, -dvz2);
                    a00 = fmaf(px,qx,a00); a01 = fmaf(px,qy,a01); a02 = fmaf(px,qz,a02);
                    a10 = fmaf(py,qx,a10); a11 = fmaf(py,qy,a11); a12 = fmaf(py,qz,a12);
                    a20 = fmaf(pz,qx,a20); a21 = fmaf(pz,qy,a21); a22 = fmaf(pz,qz,a22);
                }
            }
            finish_vertex(a00,a01,a02,a10,a11,a12,a20,a21,a22,
                          cvx2,cvy2,cvz2,dvx2,dvy2,dvz2, t, v2, out);
        }
    }
}

extern "C" void kernel_launch(void* const* d_in, const int* in_sizes, int n_in,
                              void* d_out, int out_size, void* d_ws, size_t ws_size,
                              hipStream_t stream) {
    const float* cano = (const float*)d_in[0];
    const float* defo = (const float*)d_in[1];
    const int*   nbr  = (const int*)d_in[2];
    const unsigned char* mask = (const unsigned char*)d_in[3];
    float* out = (float*)d_out;

    // Allow ~78.5 KB dynamic LDS (host-side config, idempotent).
    static bool attr_set = false;
    if (!attr_set) {
        (void)hipFuncSetAttribute((const void*)se3_extract_kernel,
                                  hipFuncAttributeMaxDynamicSharedMemorySize,
                                  LDS_BYTES);
        attr_set = true;
    }

    // 4 blocks per frame (vertex quarters); t = bid & 127; 2 blocks/CU,
    // 16 waves/CU, VGPR <= 128 (no spill).
    se3_extract_kernel<<<512, 512, LDS_BYTES, stream>>>(cano, defo, nbr, mask, out);
}